// Round 1
// baseline (530.373 us; speedup 1.0000x reference)
//
#include <hip/hip_runtime.h>
#include <math.h>

#define NNODES 50000
#define NEDGES 800000
#define CIN 64
#define CMSG 71
#define COUT 64

// ---------------------------------------------------------------------------
// init: out <- -inf  (segment_max identity; harness poisons d_out with 0xAA)
// ---------------------------------------------------------------------------
__global__ void init_out_kernel(float* __restrict__ out, int n) {
    int i = blockIdx.x * blockDim.x + threadIdx.x;
    int stride = gridDim.x * blockDim.x;
    for (; i < n; i += stride) out[i] = -INFINITY;
}

// finalize: nodes with no incoming edges stay -inf -> 0 (reference semantics)
__global__ void finalize_kernel(float* __restrict__ out, int n) {
    int i = blockIdx.x * blockDim.x + threadIdx.x;
    int stride = gridDim.x * blockDim.x;
    for (; i < n; i += stride) {
        float v = out[i];
        out[i] = (__float_as_uint(v) == 0xFF800000u) ? 0.0f : v;
    }
}

// float atomic max via int-max (val>=0) / uint-min (val<0) bit trick.
// Works against the -inf (0xFF800000) sentinel.
__device__ __forceinline__ void atomic_max_float(float* addr, float val) {
    if (val >= 0.0f) {
        atomicMax((int*)addr, __float_as_int(val));
    } else {
        atomicMin((unsigned int*)addr, __float_as_uint(val));
    }
}

// ---------------------------------------------------------------------------
// Fused edge kernel: one wave per edge per iteration.
//   msg_in = [ feat[src] (64) | pos[src] (3) | pos[dst]-pos[src] (3) | dist (1) ]
//   y = msg_in @ W[type] + b[type]   (type is wave-uniform -> uniform branch)
//   atomic-max scatter into out[dst]
// W+b staged in LDS once per block ([t][k][j] layout: per-k reads are lane-
// consecutive -> 2-way bank aliasing = free). msg feat broadcast via per-wave
// LDS buffer, block-lockstep barriers for WAR/RAW safety.
// ---------------------------------------------------------------------------
__global__ __launch_bounds__(256, 4) void edge_kernel(
    const float* __restrict__ feat, const float* __restrict__ pos,
    const float* __restrict__ W, const float* __restrict__ b,
    const int* __restrict__ ei, const int* __restrict__ ea,
    float* __restrict__ out, int nIter)
{
    __shared__ float Ws[2 * CMSG * COUT];   // 36352 B, [t][k][j]
    __shared__ float bs[2 * COUT];          // 512 B
    __shared__ float msgs[4][CIN];          // per-wave feat staging, 1024 B

    const int tid = threadIdx.x;

    // ---- stage W, b into LDS (float4, coalesced) ----
    {
        const float4* Wg4 = (const float4*)W;
        float4* Ws4 = (float4*)Ws;
        #pragma unroll 4
        for (int i = tid; i < (2 * CMSG * COUT) / 4; i += 256) Ws4[i] = Wg4[i];
        for (int i = tid; i < 2 * COUT; i += 256) bs[i] = b[i];
    }
    __syncthreads();

    const int wv = tid >> 6;
    const int lane = tid & 63;

    for (int it = 0; it < nIter; ++it) {
        const long e = ((long)it * gridDim.x + blockIdx.x) * 4 + wv;
        const bool valid = (e < NEDGES);

        int src = 0, dst = 0, t = 0;
        float f = 0.f, ps0 = 0.f, ps1 = 0.f, ps2 = 0.f;
        float d0 = 0.f, d1 = 0.f, d2 = 0.f, dist = 0.f;
        if (valid) {
            src = ei[e];
            dst = ei[NEDGES + e];
            t = ea[e];
            f = feat[(long)src * CIN + lane];          // coalesced 256B gather
            ps0 = pos[src * 3 + 0];                    // broadcast loads
            ps1 = pos[src * 3 + 1];
            ps2 = pos[src * 3 + 2];
            float pd0 = pos[dst * 3 + 0];
            float pd1 = pos[dst * 3 + 1];
            float pd2 = pos[dst * 3 + 2];
            d0 = pd0 - ps0; d1 = pd1 - ps1; d2 = pd2 - ps2;
            dist = sqrtf(d0 * d0 + d1 * d1 + d2 * d2);
        }

        __syncthreads();                 // previous iter's msg reads complete
        if (valid) msgs[wv][lane] = f;
        __syncthreads();                 // msg visible to whole wave

        if (valid) {
            float acc = bs[t * COUT + lane];
            const float* Wt = &Ws[t * CMSG * COUT];
            const float4* m4 = (const float4*)&msgs[wv][0];
            #pragma unroll
            for (int k4 = 0; k4 < 16; ++k4) {
                float4 m = m4[k4];                     // same-addr broadcast
                const float* wk = &Wt[(k4 * 4) * COUT + lane];
                acc = fmaf(m.x, wk[0],   acc);
                acc = fmaf(m.y, wk[64],  acc);
                acc = fmaf(m.z, wk[128], acc);
                acc = fmaf(m.w, wk[192], acc);
            }
            // tail: k = 64..70  (pos_src, diff, dist — wave-uniform regs)
            const float* wk = &Wt[64 * COUT + lane];
            acc = fmaf(ps0,  wk[0],   acc);
            acc = fmaf(ps1,  wk[64],  acc);
            acc = fmaf(ps2,  wk[128], acc);
            acc = fmaf(d0,   wk[192], acc);
            acc = fmaf(d1,   wk[256], acc);
            acc = fmaf(d2,   wk[320], acc);
            acc = fmaf(dist, wk[384], acc);

            atomic_max_float(&out[(long)dst * COUT + lane], acc);
        }
    }
}

extern "C" void kernel_launch(void* const* d_in, const int* in_sizes, int n_in,
                              void* d_out, int out_size, void* d_ws, size_t ws_size,
                              hipStream_t stream) {
    const float* feat = (const float*)d_in[0];
    const float* pos  = (const float*)d_in[1];
    const float* W    = (const float*)d_in[2];
    const float* b    = (const float*)d_in[3];
    const int*   ei   = (const int*)d_in[4];
    const int*   ea   = (const int*)d_in[5];
    float* out = (float*)d_out;

    const int n_out = NNODES * COUT;
    init_out_kernel<<<2048, 256, 0, stream>>>(out, n_out);

    const int grid = 2048;                     // 4 blocks/CU (LDS-capped), W
    const int edgesPerIter = grid * 4;         // restaged only 2048x = 74 MB
    const int nIter = (NEDGES + edgesPerIter - 1) / edgesPerIter;
    edge_kernel<<<grid, 256, 0, stream>>>(feat, pos, W, b, ei, ea, out, nIter);

    finalize_kernel<<<2048, 256, 0, stream>>>(out, n_out);
}

// Round 3
// 233.822 us; speedup vs baseline: 2.2683x; 2.2683x over previous
//
#include <hip/hip_runtime.h>
#include <math.h>

#define NNODES 50000
#define NEDGES 800000
#define COUT 64
#define TILE_E 64
#define NTILES (NEDGES / TILE_E)   // 12500, exact
#define RS 384                     // LDS row stride bytes (24 slots of 16B): bank-phase 0 for all rows
#define GRID 768                   // 256 CU x 3 blocks

typedef short bf16x8 __attribute__((ext_vector_type(8)));
typedef float f32x4 __attribute__((ext_vector_type(4)));

// fp32 -> bf16 RTNE
__device__ __forceinline__ unsigned short f2bf(float x) {
    union { float f; unsigned u; } v; v.f = x;
    unsigned r = v.u + 0x7fffu + ((v.u >> 16) & 1u);
    return (unsigned short)(r >> 16);
}

// order-preserving float -> uint key (max over keys == max over floats)
__device__ __forceinline__ unsigned fkey(float v) {
    unsigned u = __float_as_uint(v);
    return u ^ ((unsigned)((int)u >> 31) | 0x80000000u);
}

// out holds keys during edge kernel. key(-inf) = ~0xFF800000 = 0x007FFFFF
__global__ void init_out_kernel(unsigned* __restrict__ out, int n) {
    int i = blockIdx.x * blockDim.x + threadIdx.x;
    int stride = gridDim.x * blockDim.x;
    for (; i < n; i += stride) out[i] = 0x007FFFFFu;
}

// unmap key -> float; -inf (no incoming edge) -> 0
__global__ void finalize_kernel(float* __restrict__ out, int n) {
    int i = blockIdx.x * blockDim.x + threadIdx.x;
    int stride = gridDim.x * blockDim.x;
    for (; i < n; i += stride) {
        unsigned k = ((unsigned*)out)[i];
        unsigned u = (k & 0x80000000u) ? (k ^ 0x80000000u) : ~k;
        out[i] = (u == 0xFF800000u) ? 0.0f : __uint_as_float(u);
    }
}

// ---------------------------------------------------------------------------
// MFMA edge kernel. Per block-iter: 64 edges.
//  msg_aug[e][k], k in [80t..80t+79]: [feat(64) | ps(3) diff(3) dist | 1.0],
//  other type block zeroed; K padded to 160 (20 slots). W_aug[col][k] in LDS.
//  XOR slot swizzle (slot ^ (row&7)) with 384B row stride -> 2-way (free).
//  4 waves: wave w -> 32x32 output tile (rg=w>>1 rows, cg=w&1 cols),
//  2x2 x 5 k-steps of mfma_f32_16x16x32_bf16. Scatter: 1 uint atomicMax/elem.
// ---------------------------------------------------------------------------
__global__ __launch_bounds__(256, 3) void edge_mfma_kernel(
    const float* __restrict__ feat, const float* __restrict__ pos,
    const float* __restrict__ W, const float* __restrict__ b,
    const int* __restrict__ ei, const int* __restrict__ ea,
    unsigned* __restrict__ out)
{
    __shared__ bf16x8 Amsg[TILE_E * (RS / 16)];   // 24576 B
    __shared__ bf16x8 Wt[COUT * (RS / 16)];       // 24576 B
    __shared__ int dstv[TILE_E];

    const int tid = threadIdx.x;

    // ---- stage W_aug [col j][k] bf16, swizzled; once per block ----
    for (int idx = tid; idx < COUT * 160; idx += 256) {
        int k = idx >> 6;            // 0..159 (coalesced over j)
        int j = idx & 63;
        int t = (k >= 80);
        int kk = k - t * 80;
        float v = 0.0f;
        if (kk < 71)       v = W[(t * 71 + kk) * 64 + j];
        else if (kk == 71) v = b[t * 64 + j];
        int byte = j * RS + ((((k >> 3) ^ (j & 7)) << 4) | ((k & 7) * 2));
        *(unsigned short*)((char*)Wt + byte) = f2bf(v);
    }
    __syncthreads();

    const int e_local = tid >> 2, c = tid & 3;
    const int lane = tid & 63, w = tid >> 6;
    const int rg = w >> 1, cg = w & 1;
    const int la = lane & 15, lh = lane >> 4;
    const bf16x8 zero8 = {0, 0, 0, 0, 0, 0, 0, 0};

    for (int tile = blockIdx.x; tile < NTILES; tile += gridDim.x) {
        // ---------------- stage 64 edges ----------------
        const long e = (long)tile * TILE_E + e_local;
        const int src = ei[e];
        const int t = ea[e];
        const int ot = 1 - t;
        char* Ab = (char*)Amsg;
        const int rbase = e_local * RS;
        const int rx = e_local & 7;

        // 16 feat floats -> 2 bf16 slots
        const float4* fp = (const float4*)(feat + (long)src * 64 + c * 16);
        float4 f0 = fp[0], f1 = fp[1], f2 = fp[2], f3 = fp[3];
        union { bf16x8 v; unsigned short u[8]; } p0, p1;
        p0.u[0] = f2bf(f0.x); p0.u[1] = f2bf(f0.y); p0.u[2] = f2bf(f0.z); p0.u[3] = f2bf(f0.w);
        p0.u[4] = f2bf(f1.x); p0.u[5] = f2bf(f1.y); p0.u[6] = f2bf(f1.z); p0.u[7] = f2bf(f1.w);
        p1.u[0] = f2bf(f2.x); p1.u[1] = f2bf(f2.y); p1.u[2] = f2bf(f2.z); p1.u[3] = f2bf(f2.w);
        p1.u[4] = f2bf(f3.x); p1.u[5] = f2bf(f3.y); p1.u[6] = f2bf(f3.z); p1.u[7] = f2bf(f3.w);
        int s0 = t * 10 + c * 2;
        *(bf16x8*)(Ab + rbase + ((s0 ^ rx) << 4))       = p0.v;
        *(bf16x8*)(Ab + rbase + (((s0 + 1) ^ rx) << 4)) = p1.v;
        // zero the mirror slots in the other type block
        int z0 = ot * 10 + c * 2;
        *(bf16x8*)(Ab + rbase + ((z0 ^ rx) << 4))       = zero8;
        *(bf16x8*)(Ab + rbase + (((z0 + 1) ^ rx) << 4)) = zero8;

        if (c == 0) {
            int dst = ei[NEDGES + e];
            float ps0 = pos[src * 3], ps1 = pos[src * 3 + 1], ps2 = pos[src * 3 + 2];
            float d0 = pos[dst * 3] - ps0, d1 = pos[dst * 3 + 1] - ps1, d2 = pos[dst * 3 + 2] - ps2;
            float dist = sqrtf(d0 * d0 + d1 * d1 + d2 * d2);
            union { bf16x8 v; unsigned short u[8]; } pt;
            pt.u[0] = f2bf(ps0); pt.u[1] = f2bf(ps1); pt.u[2] = f2bf(ps2);
            pt.u[3] = f2bf(d0);  pt.u[4] = f2bf(d1);  pt.u[5] = f2bf(d2);
            pt.u[6] = f2bf(dist); pt.u[7] = f2bf(1.0f);
            *(bf16x8*)(Ab + rbase + (((t * 10 + 8) ^ rx) << 4)) = pt.v;
        } else if (c == 1) {
            *(bf16x8*)(Ab + rbase + (((ot * 10 + 8) ^ rx) << 4)) = zero8;
        } else if (c == 2) {
            *(bf16x8*)(Ab + rbase + (((ot * 10 + 9) ^ rx) << 4)) = zero8;
        } else {
            *(bf16x8*)(Ab + rbase + (((t * 10 + 9) ^ rx) << 4)) = zero8;
            dstv[e_local] = ei[NEDGES + e];
        }
        __syncthreads();

        // ---------------- mfma: 32x32 tile per wave ----------------
        f32x4 acc00 = {0,0,0,0}, acc01 = {0,0,0,0}, acc10 = {0,0,0,0}, acc11 = {0,0,0,0};
        const char* Ac = (const char*)Amsg;
        const char* Wc = (const char*)Wt;
        const int r0 = rg * 32 + la, r1 = r0 + 16;
        const int c0 = cg * 32 + la, c1 = c0 + 16;
        const int sx = la & 7;                      // (row&7) == (col&7) == la&7
        #pragma unroll
        for (int ks = 0; ks < 5; ++ks) {
            int slot = ks * 4 + lh;
            int so = (slot ^ sx) << 4;
            bf16x8 a0 = *(const bf16x8*)(Ac + r0 * RS + so);
            bf16x8 a1 = *(const bf16x8*)(Ac + r1 * RS + so);
            bf16x8 b0 = *(const bf16x8*)(Wc + c0 * RS + so);
            bf16x8 b1 = *(const bf16x8*)(Wc + c1 * RS + so);
            acc00 = __builtin_amdgcn_mfma_f32_16x16x32_bf16(a0, b0, acc00, 0, 0, 0);
            acc01 = __builtin_amdgcn_mfma_f32_16x16x32_bf16(a0, b1, acc01, 0, 0, 0);
            acc10 = __builtin_amdgcn_mfma_f32_16x16x32_bf16(a1, b0, acc10, 0, 0, 0);
            acc11 = __builtin_amdgcn_mfma_f32_16x16x32_bf16(a1, b1, acc11, 0, 0, 0);
        }

        // ---------------- scatter: C row = lh*4 + reg, col = la ----------------
        const int col0 = cg * 32 + la, col1 = col0 + 16;
        #pragma unroll
        for (int i = 0; i < 4; ++i) {
            int er0 = rg * 32 + lh * 4 + i;
            int er1 = er0 + 16;
            int d0i = dstv[er0];
            int d1i = dstv[er1];
            atomicMax(out + (long)d0i * COUT + col0, fkey(acc00[i]));
            atomicMax(out + (long)d0i * COUT + col1, fkey(acc01[i]));
            atomicMax(out + (long)d1i * COUT + col0, fkey(acc10[i]));
            atomicMax(out + (long)d1i * COUT + col1, fkey(acc11[i]));
        }
        __syncthreads();   // protect Amsg/dstv before next iter's staging
    }
}

extern "C" void kernel_launch(void* const* d_in, const int* in_sizes, int n_in,
                              void* d_out, int out_size, void* d_ws, size_t ws_size,
                              hipStream_t stream) {
    const float* feat = (const float*)d_in[0];
    const float* pos  = (const float*)d_in[1];
    const float* W    = (const float*)d_in[2];
    const float* b    = (const float*)d_in[3];
    const int*   ei   = (const int*)d_in[4];
    const int*   ea   = (const int*)d_in[5];

    const int n_out = NNODES * COUT;
    init_out_kernel<<<1024, 256, 0, stream>>>((unsigned*)d_out, n_out);
    edge_mfma_kernel<<<GRID, 256, 0, stream>>>(feat, pos, W, b, ei, ea, (unsigned*)d_out);
    finalize_kernel<<<1024, 256, 0, stream>>>((float*)d_out, n_out);
}